// Round 2
// baseline (1583.702 us; speedup 1.0000x reference)
//
#include <hip/hip_runtime.h>
#include <stdint.h>

#define KOFF 27
#define CIN 64
#define COUT 128
#define EPS 1e-5f

using frag_ab = __attribute__((ext_vector_type(8))) short;
using frag_cd = __attribute__((ext_vector_type(4))) float;

__device__ __forceinline__ float bf2f(unsigned short u) {
  union { unsigned int i; float f; } x; x.i = ((unsigned int)u) << 16; return x.f;
}
__device__ __forceinline__ unsigned short f2bf(float f) {
  union { float f; unsigned int i; } x; x.f = f;
  unsigned int u = x.i;
  u += 0x7fffu + ((u >> 16) & 1u);   // round-to-nearest-even
  return (unsigned short)(u >> 16);
}

// ---------------------------------------------------------------------------
// Gather-GEMM: Y[row] = sum_k X[nbr[k][row]] @ W[k].
// X: fp32 (XF32) or bf16; W pre-transposed+bf16: Wt[k][co][ci]; Y: bf16 or
// fp32 (OF32). fp32 accumulation via mfma_f32_16x16x32_bf16.
// BLOCK_M=128, BLOCK_N=COUT=128, 256 thr = 4 waves (2x2 of 64x64/wave).
// K staged in BK=64 chunks -> LDS 2*128*72*2 = 36.9 KB.
// ---------------------------------------------------------------------------
template <int CI, bool GATHER, bool XF32, bool OF32>
__global__ __launch_bounds__(256, 2) void conv_kernel(
    const void* __restrict__ Xv, const int* __restrict__ nbr,
    const unsigned short* __restrict__ Wt, void* __restrict__ Yv,
    int n, int koff) {
  constexpr int LDA = 72;  // 64 + 8 bf16 pad
  __shared__ unsigned short Alds[128 * LDA];
  __shared__ unsigned short Blds[128 * LDA];

  const int tid = threadIdx.x;
  const int lane = tid & 63;
  const int wave = tid >> 6;
  const int row0 = blockIdx.x * 128;
  const int wrow = (wave >> 1) * 64;
  const int wcol = (wave & 1) * 64;
  const int m = lane & 15;
  const int q = lane >> 4;

  frag_cd acc[4][4];
#pragma unroll
  for (int i = 0; i < 4; ++i)
#pragma unroll
    for (int j = 0; j < 4; ++j) acc[i][j] = (frag_cd){0.f, 0.f, 0.f, 0.f};

  for (int ko = 0; ko < koff; ++ko) {
    const int* nb = GATHER ? (nbr + (size_t)ko * n) : nullptr;
    const unsigned short* wt = Wt + (size_t)ko * (128 * CI);
#pragma unroll
    for (int kc = 0; kc < CI / 64; ++kc) {
      __syncthreads();  // previous LDS use complete
      // stage A + B: 128 rows x 8 segments (8 ch each); 4 units/thread
#pragma unroll
      for (int c = 0; c < 4; ++c) {
        const int u = tid + 256 * c;
        const int row = u >> 3;
        const int seg = u & 7;
        const int grow = row0 + row;
        int idx = -1;
        if (grow < n) idx = GATHER ? nb[grow] : grow;
        uint4 av = make_uint4(0u, 0u, 0u, 0u);
        if (idx >= 0) {
          if (XF32) {
            const float* xp = (const float*)Xv + (size_t)idx * CI + kc * 64 + seg * 8;
            float4 lo = *(const float4*)xp;
            float4 hi = *(const float4*)(xp + 4);
            av.x = (unsigned int)f2bf(lo.x) | ((unsigned int)f2bf(lo.y) << 16);
            av.y = (unsigned int)f2bf(lo.z) | ((unsigned int)f2bf(lo.w) << 16);
            av.z = (unsigned int)f2bf(hi.x) | ((unsigned int)f2bf(hi.y) << 16);
            av.w = (unsigned int)f2bf(hi.z) | ((unsigned int)f2bf(hi.w) << 16);
          } else {
            av = *(const uint4*)((const unsigned short*)Xv + (size_t)idx * CI + kc * 64 + seg * 8);
          }
        }
        *(uint4*)(Alds + row * LDA + seg * 8) = av;
        uint4 bv = *(const uint4*)(wt + row * CI + kc * 64 + seg * 8);
        *(uint4*)(Blds + row * LDA + seg * 8) = bv;
      }
      __syncthreads();
      // MFMA: 2 K-steps of 32 over this 64-chunk
#pragma unroll
      for (int kk = 0; kk < 64; kk += 32) {
        frag_ab a[4], b[4];
        const int col = kk + q * 8;
#pragma unroll
        for (int i = 0; i < 4; ++i)
          a[i] = *(const frag_ab*)(Alds + (wrow + 16 * i + m) * LDA + col);
#pragma unroll
        for (int j = 0; j < 4; ++j)
          b[j] = *(const frag_ab*)(Blds + (wcol + 16 * j + m) * LDA + col);
#pragma unroll
        for (int i = 0; i < 4; ++i)
#pragma unroll
          for (int j = 0; j < 4; ++j)
            acc[i][j] = __builtin_amdgcn_mfma_f32_16x16x32_bf16(a[i], b[j],
                                                                acc[i][j], 0, 0, 0);
      }
    }
  }

  // epilogue: C/D layout col=lane&15, row=(lane>>4)*4+reg
#pragma unroll
  for (int i = 0; i < 4; ++i) {
#pragma unroll
    for (int r = 0; r < 4; ++r) {
      const int grow = row0 + wrow + 16 * i + q * 4 + r;
      if (grow < n) {
#pragma unroll
        for (int j = 0; j < 4; ++j) {
          const int gcol = wcol + 16 * j + m;
          if (OF32)
            ((float*)Yv)[(size_t)grow * COUT + gcol] = acc[i][j][r];
          else
            ((unsigned short*)Yv)[(size_t)grow * COUT + gcol] = f2bf(acc[i][j][r]);
        }
      }
    }
  }
}

// dst[k][co][ci] (bf16) = src[k][ci][co] (fp32)
__global__ void transpose_w(const float* __restrict__ src,
                            unsigned short* __restrict__ dst, int kk, int ci,
                            int co) {
  int gid = blockIdx.x * blockDim.x + threadIdx.x;
  int total = kk * ci * co;
  if (gid >= total) return;
  int per = ci * co;
  int k = gid / per;
  int rem = gid - k * per;
  int o = rem / ci;
  int i = rem - o * ci;
  dst[gid] = f2bf(src[(size_t)k * per + (size_t)i * co + o]);
}

// per-channel sum / sumsq of [n][COUT] -> sums[0:128]=sum, [128:256]=sumsq
template <bool F32>
__global__ void stats_kernel(const void* __restrict__ xv,
                             float* __restrict__ sums, int n) {
  int t = threadIdx.x;
  int c2 = (t & 63) * 2;
  int row = blockIdx.x * 4 + (t >> 6);
  const int stride = gridDim.x * 4;
  float s0 = 0.f, s1 = 0.f, q0 = 0.f, q1 = 0.f;
  for (; row < n; row += stride) {
    float f0, f1;
    if (F32) {
      const float* x = (const float*)xv + (size_t)row * COUT + c2;
      f0 = x[0]; f1 = x[1];
    } else {
      unsigned int v = *(const unsigned int*)((const unsigned short*)xv + (size_t)row * COUT + c2);
      f0 = bf2f((unsigned short)(v & 0xffffu));
      f1 = bf2f((unsigned short)(v >> 16));
    }
    s0 += f0; q0 += f0 * f0;
    s1 += f1; q1 += f1 * f1;
  }
  atomicAdd(&sums[c2], s0);
  atomicAdd(&sums[c2 + 1], s1);
  atomicAdd(&sums[COUT + c2], q0);
  atomicAdd(&sums[COUT + c2 + 1], q1);
}

__global__ void finalize_kernel(const float* __restrict__ sums,
                                const float* __restrict__ gamma,
                                const float* __restrict__ beta,
                                float* __restrict__ scale,
                                float* __restrict__ shift, int n) {
  int c = threadIdx.x;
  float inv_n = 1.f / (float)n;
  float mean = sums[c] * inv_n;
  float var = sums[COUT + c] * inv_n - mean * mean;
  float sc = gamma[c] * rsqrtf(var + EPS);
  scale[c] = sc;
  shift[c] = beta[c] - mean * sc;
}

// in-place bf16 x = relu(x*scale + shift), 8 bf16 per thread
__global__ void norm_relu_kernel(unsigned short* __restrict__ x,
                                 const float* __restrict__ scale,
                                 const float* __restrict__ shift, int total8) {
  int gid = blockIdx.x * 256 + threadIdx.x;
  if (gid >= total8) return;
  size_t i = (size_t)gid * 8;
  int c0 = (int)(i & 127);
  uint4 v = *(const uint4*)(x + i);
  unsigned int w[4] = {v.x, v.y, v.z, v.w};
  unsigned int wo[4];
#pragma unroll
  for (int e = 0; e < 4; ++e) {
    int c = c0 + 2 * e;
    float f0 = bf2f((unsigned short)(w[e] & 0xffffu));
    float f1 = bf2f((unsigned short)(w[e] >> 16));
    f0 = fmaxf(f0 * scale[c] + shift[c], 0.f);
    f1 = fmaxf(f1 * scale[c + 1] + shift[c + 1], 0.f);
    wo[e] = (unsigned int)f2bf(f0) | ((unsigned int)f2bf(f1) << 16);
  }
  *(uint4*)(x + i) = make_uint4(wo[0], wo[1], wo[2], wo[3]);
}

// out(fp32, in-place on h2) = relu(h2*scale2+shift2 + s*scaled+shiftd)
__global__ void final_kernel(float* __restrict__ h2,
                             const unsigned short* __restrict__ s,
                             const float* __restrict__ scale2,
                             const float* __restrict__ shift2,
                             const float* __restrict__ scaled,
                             const float* __restrict__ shiftd, int total4) {
  int gid = blockIdx.x * 256 + threadIdx.x;
  if (gid >= total4) return;
  size_t i = (size_t)gid * 4;
  int c = (int)(i & 127);
  float4 a = *(const float4*)(h2 + i);
  uint2 sv = *(const uint2*)(s + i);
  float b0 = bf2f((unsigned short)(sv.x & 0xffffu));
  float b1 = bf2f((unsigned short)(sv.x >> 16));
  float b2 = bf2f((unsigned short)(sv.y & 0xffffu));
  float b3 = bf2f((unsigned short)(sv.y >> 16));
  float4 o;
  o.x = fmaxf(a.x * scale2[c] + shift2[c] + b0 * scaled[c] + shiftd[c], 0.f);
  o.y = fmaxf(a.y * scale2[c + 1] + shift2[c + 1] + b1 * scaled[c + 1] + shiftd[c + 1], 0.f);
  o.z = fmaxf(a.z * scale2[c + 2] + shift2[c + 2] + b2 * scaled[c + 2] + shiftd[c + 2], 0.f);
  o.w = fmaxf(a.w * scale2[c + 3] + shift2[c + 3] + b3 * scaled[c + 3] + shiftd[c + 3], 0.f);
  *(float4*)(h2 + i) = o;
}

extern "C" void kernel_launch(void* const* d_in, const int* in_sizes, int n_in,
                              void* d_out, int out_size, void* d_ws,
                              size_t ws_size, hipStream_t stream) {
  (void)n_in; (void)out_size; (void)ws_size;
  const float* feats = (const float*)d_in[0];
  const int* nbr1 = (const int*)d_in[1];
  const int* nbr2 = (const int*)d_in[2];
  const float* W1 = (const float*)d_in[3];
  const float* W2 = (const float*)d_in[4];
  const float* Wd = (const float*)d_in[5];
  const float* g1 = (const float*)d_in[6];
  const float* b1 = (const float*)d_in[7];
  const float* g2 = (const float*)d_in[8];
  const float* b2 = (const float*)d_in[9];
  const float* gd = (const float*)d_in[10];
  const float* bd = (const float*)d_in[11];

  const int n = in_sizes[0] / CIN;  // 200000

  // ws layout (bytes): Wt1[442368] Wt2[884736] Wdt[16384] h1_bf16[51.2e6]
  //                    s_bf16[51.2e6] stats[~3 KB]  -> ~103.75 MB total
  char* ws = (char*)d_ws;
  unsigned short* Wt1 = (unsigned short*)(ws);
  unsigned short* Wt2 = (unsigned short*)(ws + 442368);
  unsigned short* Wdt = (unsigned short*)(ws + 1327104);
  unsigned short* h1 = (unsigned short*)(ws + 1343488);
  unsigned short* sX = (unsigned short*)(ws + 52543488);
  float* sums1 = (float*)(ws + 103743488);
  float* sums2 = sums1 + 2 * COUT;
  float* sumsd = sums1 + 4 * COUT;
  float* scale1 = sums1 + 6 * COUT;
  float* shift1 = scale1 + COUT;
  float* scale2 = scale1 + 2 * COUT;
  float* shift2 = scale1 + 3 * COUT;
  float* scaled = scale1 + 4 * COUT;
  float* shiftd = scale1 + 5 * COUT;

  float* h2 = (float*)d_out;  // conv2 output lives in d_out (fp32)

  hipMemsetAsync(sums1, 0, 6 * COUT * sizeof(float), stream);

  transpose_w<<<(KOFF * CIN * COUT + 255) / 256, 256, 0, stream>>>(W1, Wt1, KOFF, CIN, COUT);
  transpose_w<<<(KOFF * COUT * COUT + 255) / 256, 256, 0, stream>>>(W2, Wt2, KOFF, COUT, COUT);
  transpose_w<<<(CIN * COUT + 255) / 256, 256, 0, stream>>>(Wd, Wdt, 1, CIN, COUT);

  const int mblocks = (n + 127) / 128;
  conv_kernel<CIN, true, true, false><<<mblocks, 256, 0, stream>>>(feats, nbr1, Wt1, h1, n, KOFF);
  conv_kernel<CIN, false, true, false><<<mblocks, 256, 0, stream>>>(feats, nullptr, Wdt, sX, n, 1);

  stats_kernel<false><<<512, 256, 0, stream>>>(h1, sums1, n);
  finalize_kernel<<<1, COUT, 0, stream>>>(sums1, g1, b1, scale1, shift1, n);

  const int total8 = n * COUT / 8;
  norm_relu_kernel<<<(total8 + 255) / 256, 256, 0, stream>>>(h1, scale1, shift1, total8);

  conv_kernel<COUT, true, false, true><<<mblocks, 256, 0, stream>>>(h1, nbr2, Wt2, h2, n, KOFF);

  stats_kernel<true><<<512, 256, 0, stream>>>(h2, sums2, n);
  stats_kernel<false><<<512, 256, 0, stream>>>(sX, sumsd, n);
  finalize_kernel<<<1, COUT, 0, stream>>>(sums2, g2, b2, scale2, shift2, n);
  finalize_kernel<<<1, COUT, 0, stream>>>(sumsd, gd, bd, scaled, shiftd, n);

  const int total4 = n * COUT / 4;
  final_kernel<<<(total4 + 255) / 256, 256, 0, stream>>>(h2, sX, scale2, shift2, scaled, shiftd, total4);
}